// Round 3
// baseline (530.335 us; speedup 1.0000x reference)
//
#include <hip/hip_runtime.h>
#include <hip/hip_cooperative_groups.h>
#include <math.h>

namespace cg = cooperative_groups;

#define NL 16
#define TS (1u << 19)
#define TMASK (TS - 1u)
#define PRIME 2654435761u

// Sort bins: g (1 bit) | iy_finest (9 bits) | ix_chunk (3 bits) = 8192 bins.
// hash = ix ^ (iy*PRIME): x-adjacent corners share cache lines, y-adjacent
// corners jump randomly -> cluster by (g, row, x-chunk).
#define NBINS 8192
#define BIN_GBIT 12

typedef float f4 __attribute__((ext_vector_type(4)));   // nontemporal-store-able

struct ScalePack { float s[NL]; };

__device__ __forceinline__ unsigned bin_of(float px, float py, int g) {
    int iy = (int)(py * 511.0f); iy = iy < 0 ? 0 : (iy > 511 ? 511 : iy);
    int ix = (int)(px * 511.0f); ix = ix < 0 ? 0 : (ix > 511 ? 511 : ix);
    return ((unsigned)g << BIN_GBIT) | ((unsigned)iy << 3) | ((unsigned)ix >> 6);
}

// ---------------- fused cooperative prep: zero + hist + scan + scatter ------
// 2 points per thread held in registers across all phases (x/hidx read ONCE).
__global__ __launch_bounds__(256, 8)
void k_prep(const float2* __restrict__ x, const int* __restrict__ hidx,
            unsigned* __restrict__ hist,          // NBINS, used as cursors after scan
            float2* __restrict__ sxy, unsigned* __restrict__ smeta, int N)
{
    cg::grid_group grid = cg::this_grid();
    int tid = blockIdx.x * 256 + threadIdx.x;
    int nth = gridDim.x * 256;

    // phase 0: zero hist
    for (int i = tid; i < NBINS; i += nth) hist[i] = 0u;
    grid.sync();

    // phase 1: histogram; keep point data in registers
    float2 p0, p1; int g0 = 0, g1 = 0; unsigned b0 = 0, b1 = 0;
    int n0 = -1, n1 = -1;
    int i0 = tid, i1 = tid + nth;
    if (i0 < N) {
        p0 = x[i0]; g0 = hidx[i0]; b0 = bin_of(p0.x, p0.y, g0); n0 = i0;
        atomicAdd(&hist[b0], 1u);
    }
    if (i1 < N) {
        p1 = x[i1]; g1 = hidx[i1]; b1 = bin_of(p1.x, p1.y, g1); n1 = i1;
        atomicAdd(&hist[b1], 1u);
    }
    grid.sync();

    // phase 2: exclusive scan of NBINS by block 0 (256 thr x 32 bins each)
    if (blockIdx.x == 0) {
        __shared__ unsigned part[256];
        unsigned v[32];
        unsigned s = 0;
        #pragma unroll
        for (int i = 0; i < 32; ++i) { v[i] = hist[threadIdx.x * 32 + i]; s += v[i]; }
        part[threadIdx.x] = s;
        __syncthreads();
        for (int d = 1; d < 256; d <<= 1) {
            unsigned add = (threadIdx.x >= (unsigned)d) ? part[threadIdx.x - d] : 0u;
            __syncthreads();
            part[threadIdx.x] += add;
            __syncthreads();
        }
        unsigned base = threadIdx.x ? part[threadIdx.x - 1] : 0u;
        #pragma unroll
        for (int i = 0; i < 32; ++i) {
            unsigned c = v[i];
            hist[threadIdx.x * 32 + i] = base;
            base += c;
        }
    }
    grid.sync();

    // phase 3: scatter (hist now holds running cursors)
    if (n0 >= 0) {
        unsigned pos = atomicAdd(&hist[b0], 1u);
        sxy[pos] = p0;
        smeta[pos] = (unsigned)n0 | ((unsigned)g0 << 24);
    }
    if (n1 >= 0) {
        unsigned pos = atomicAdd(&hist[b1], 1u);
        sxy[pos] = p1;
        smeta[pos] = (unsigned)n1 | ((unsigned)g1 << 24);
    }
}

// ---------------- legacy 4-kernel prep (fallback) ---------------------------
__global__ __launch_bounds__(256)
void k_zero(unsigned* __restrict__ p, int n) {
    int i = blockIdx.x * blockDim.x + threadIdx.x;
    if (i < n) p[i] = 0u;
}

__global__ __launch_bounds__(256)
void k_hist(const float2* __restrict__ x, const int* __restrict__ hidx,
            unsigned* __restrict__ hist, int N)
{
    int n = blockIdx.x * blockDim.x + threadIdx.x;
    if (n >= N) return;
    float2 p = x[n];
    atomicAdd(&hist[bin_of(p.x, p.y, hidx[n])], 1u);
}

__global__ __launch_bounds__(1024)
void k_scan(const unsigned* __restrict__ hist, unsigned* __restrict__ offs)
{
    __shared__ unsigned partial[1024];
    int t = threadIdx.x;
    unsigned v[8];
    unsigned s = 0;
    #pragma unroll
    for (int i = 0; i < 8; ++i) { v[i] = hist[t * 8 + i]; s += v[i]; }
    partial[t] = s;
    __syncthreads();
    for (int d = 1; d < 1024; d <<= 1) {
        unsigned add = (t >= d) ? partial[t - d] : 0u;
        __syncthreads();
        partial[t] += add;
        __syncthreads();
    }
    unsigned base = (t == 0) ? 0u : partial[t - 1];
    #pragma unroll
    for (int i = 0; i < 8; ++i) { offs[t * 8 + i] = base; base += v[i]; }
}

__global__ __launch_bounds__(256)
void k_scatter(const float2* __restrict__ x, const int* __restrict__ hidx,
               unsigned* __restrict__ offs,
               float2* __restrict__ sxy, unsigned* __restrict__ smeta, int N)
{
    int n = blockIdx.x * blockDim.x + threadIdx.x;
    if (n >= N) return;
    float2 p = x[n];
    int g = hidx[n];
    unsigned b = bin_of(p.x, p.y, g);
    unsigned pos = atomicAdd(&offs[b], 1u);
    sxy[pos] = p;
    smeta[pos] = (unsigned)n | ((unsigned)g << 24);
}

// ---------------- main gather kernel over sorted points ---------------------
__global__ __launch_bounds__(256)
void hashgrid2d_sorted(const float2* __restrict__ sxy,
                       const unsigned* __restrict__ smeta,
                       const float2* __restrict__ feat,
                       float4* __restrict__ out,
                       ScalePack sp, int N)
{
    // Bijective XCD-chunked swizzle: each XCD's L2 owns a contiguous y-band.
    int nwg = gridDim.x;
    int orig = blockIdx.x;
    int q = nwg >> 3, r = nwg & 7;
    int xcd = orig & 7, loc = orig >> 3;
    int bid = (xcd < r ? xcd * (q + 1) : r * (q + 1) + (xcd - r) * q) + loc;

    int n = bid * 256 + (int)threadIdx.x;
    if (n >= N) return;

    float2 p = sxy[n];
    unsigned meta = smeta[n];
    int g  = (int)(meta >> 24);
    int no = (int)(meta & 0xFFFFFFu);
    float px = p.x, py = p.y;
    const float2* fb = feat + (size_t)g * ((size_t)NL * TS);

    float of[2 * NL];

    #pragma unroll 4
    for (int l = 0; l < NL; ++l) {
        float s  = sp.s[l];
        float fx = px * s;
        float fy = py * s;
        float fx0 = floorf(fx), fy0 = floorf(fy);
        float wx = fx - fx0, wy = fy - fy0;
        unsigned ix = (unsigned)(int)fx0;
        unsigned iy = (unsigned)(int)fy0;
        unsigned hy0 = iy * PRIME;
        unsigned hy1 = (iy + 1u) * PRIME;

        const float2* tab = fb + (size_t)l * TS;
        float2 c00 = tab[( ix       ^ hy0) & TMASK];
        float2 c10 = tab[((ix + 1u) ^ hy0) & TMASK];
        float2 c01 = tab[( ix       ^ hy1) & TMASK];
        float2 c11 = tab[((ix + 1u) ^ hy1) & TMASK];

        float w00 = (1.f - wx) * (1.f - wy);
        float w10 = wx * (1.f - wy);
        float w01 = (1.f - wx) * wy;
        float w11 = wx * wy;

        of[2 * l]     = w00 * c00.x + w10 * c10.x + w01 * c01.x + w11 * c11.x;
        of[2 * l + 1] = w00 * c00.y + w10 * c10.y + w01 * c01.y + w11 * c11.y;
    }

    // Nontemporal: 125 MB output stream must not evict table lines from L2.
    f4* op = reinterpret_cast<f4*>(out + (size_t)no * 8);
    #pragma unroll
    for (int qq = 0; qq < 8; ++qq) {
        f4 v = { of[4 * qq], of[4 * qq + 1], of[4 * qq + 2], of[4 * qq + 3] };
        __builtin_nontemporal_store(v, op + qq);
    }
}

// ---------------- direct fallback (no workspace) ----------------------------
__global__ __launch_bounds__(256)
void hashgrid2d_fwd(const float2* __restrict__ x,
                    const float2* __restrict__ feat,
                    const int* __restrict__ hidx,
                    float4* __restrict__ out,
                    ScalePack sp, int N)
{
    int n = blockIdx.x * blockDim.x + threadIdx.x;
    if (n >= N) return;

    float2 p = x[n];
    float px = p.x, py = p.y;
    int g = hidx[n];
    const float2* fb = feat + (size_t)g * ((size_t)NL * TS);

    float of[2 * NL];

    #pragma unroll 4
    for (int l = 0; l < NL; ++l) {
        float s  = sp.s[l];
        float fx = px * s;
        float fy = py * s;
        float fx0 = floorf(fx), fy0 = floorf(fy);
        float wx = fx - fx0, wy = fy - fy0;
        unsigned ix = (unsigned)(int)fx0;
        unsigned iy = (unsigned)(int)fy0;
        unsigned hy0 = iy * PRIME;
        unsigned hy1 = (iy + 1u) * PRIME;

        const float2* tab = fb + (size_t)l * TS;
        float2 c00 = tab[( ix       ^ hy0) & TMASK];
        float2 c10 = tab[((ix + 1u) ^ hy0) & TMASK];
        float2 c01 = tab[( ix       ^ hy1) & TMASK];
        float2 c11 = tab[((ix + 1u) ^ hy1) & TMASK];

        float w00 = (1.f - wx) * (1.f - wy);
        float w10 = wx * (1.f - wy);
        float w01 = (1.f - wx) * wy;
        float w11 = wx * wy;

        of[2 * l]     = w00 * c00.x + w10 * c10.x + w01 * c01.x + w11 * c11.x;
        of[2 * l + 1] = w00 * c00.y + w10 * c10.y + w01 * c01.y + w11 * c11.y;
    }

    float4* op = out + (size_t)n * 8;
    #pragma unroll
    for (int qq = 0; qq < 8; ++qq)
        op[qq] = make_float4(of[4 * qq], of[4 * qq + 1], of[4 * qq + 2], of[4 * qq + 3]);
}

extern "C" void kernel_launch(void* const* d_in, const int* in_sizes, int n_in,
                              void* d_out, int out_size, void* d_ws, size_t ws_size,
                              hipStream_t stream) {
    const float2* x    = (const float2*)d_in[0];   // fp32, (N,2)
    const float2* feat = (const float2*)d_in[1];   // fp32, (2,16,T,2)
    const int*    hidx = (const int*)d_in[2];      // int32, (N,1)
    int N = in_sizes[0] / 2;

    // Replicate reference _resolutions() exactly (double log/exp/pow, same
    // libm as CPython, truncating int()). Levels 3,6,9,12,15 are 1 ulp off
    // exact powers of two — do not hardcode.
    ScalePack sp;
    double b = exp((log(512.0) - log(16.0)) / 15.0);
    for (int i = 0; i < NL; ++i) {
        int r = (int)(16.0 * pow(b, (double)i));
        sp.s[i] = (float)(r - 1);
    }

    int threads = 256;
    int blocks = (N + threads - 1) / threads;

    size_t histB = (size_t)NBINS * 4;
    size_t offB  = (size_t)NBINS * 4;
    size_t xyB   = (size_t)N * 8;
    size_t metaB = (size_t)N * 4;
    size_t need  = histB + offB + xyB + metaB;   // ~12.06 MB at N=1e6

    if (d_ws != nullptr && ws_size >= need) {
        unsigned* hist  = (unsigned*)d_ws;
        unsigned* offs  = hist + NBINS;
        float2*   sxy   = (float2*)((char*)d_ws + histB + offB);
        unsigned* smeta = (unsigned*)((char*)d_ws + histB + offB + xyB);

        // Co-residency check for cooperative launch (host-only queries; cached).
        static int coopGrid = -2;                  // -2 = unqueried
        if (coopGrid == -2) {
            int nCU = 0, occ = 0;
            if (hipDeviceGetAttribute(&nCU, hipDeviceAttributeMultiprocessorCount, 0)
                    == hipSuccess &&
                hipOccupancyMaxActiveBlocksPerMultiprocessor(
                    &occ, (const void*)k_prep, 256, 0) == hipSuccess &&
                nCU > 0 && occ > 0)
                coopGrid = nCU * occ;
            else
                coopGrid = -1;
        }

        bool coop_ok = false;
        if (coopGrid > 0) {
            int grid = coopGrid > 2048 ? 2048 : coopGrid;
            if ((size_t)grid * 512 >= (size_t)N) {   // 2 points/thread must cover N
                const float2* xa = x; const int* ha = hidx;
                unsigned* hi = hist; float2* sa = sxy; unsigned* sm = smeta; int Na = N;
                void* args[] = { &xa, &ha, &hi, &sa, &sm, &Na };
                if (hipLaunchCooperativeKernel((const void*)k_prep, dim3(grid),
                                               dim3(256), args, 0, stream)
                        == hipSuccess)
                    coop_ok = true;
            }
        }

        if (!coop_ok) {
            hipLaunchKernelGGL(k_zero, dim3((NBINS + 255) / 256), dim3(256), 0, stream,
                               hist, NBINS);
            hipLaunchKernelGGL(k_hist, dim3(blocks), dim3(threads), 0, stream,
                               x, hidx, hist, N);
            hipLaunchKernelGGL(k_scan, dim3(1), dim3(1024), 0, stream, hist, offs);
            hipLaunchKernelGGL(k_scatter, dim3(blocks), dim3(threads), 0, stream,
                               x, hidx, offs, sxy, smeta, N);
        }

        hipLaunchKernelGGL(hashgrid2d_sorted, dim3(blocks), dim3(threads), 0, stream,
                           sxy, smeta, feat, (float4*)d_out, sp, N);
    } else {
        hipLaunchKernelGGL(hashgrid2d_fwd, dim3(blocks), dim3(threads), 0, stream,
                           x, feat, hidx, (float4*)d_out, sp, N);
    }
}

// Round 4
// 447.703 us; speedup vs baseline: 1.1846x; 1.1846x over previous
//
#include <hip/hip_runtime.h>
#include <math.h>

#define NL 16
#define TS (1u << 19)
#define TMASK (TS - 1u)
#define PRIME 2654435761u

// Spatial bins: g (1 bit) | iy_finest (9 bits) | ix_chunk (3 bits) = 8192 bins.
// hash = ix ^ (iy*PRIME): x-adjacent corners share cache lines, y-adjacent
// corners jump randomly -> cluster by (g, row, x-chunk).
// Fixed-capacity bucket placement (CAP = 192 ~ 1.6x mean fill of 122):
// one atomic pass instead of hist+scan+scatter. Overflow (P ~ 1e-10/bin)
// spills to a guaranteed-capacity tail region processed identically.
#define NBINS 8192
#define BIN_GBIT 12
#define CAP 192                      // 3 full waves; waves never straddle bins
#define SLOTS (NBINS * CAP)          // 1,572,864

typedef float f4 __attribute__((ext_vector_type(4)));   // nontemporal-store-able

struct ScalePack { float s[NL]; };

__device__ __forceinline__ unsigned bin_of(float px, float py, int g) {
    int iy = (int)(py * 511.0f); iy = iy < 0 ? 0 : (iy > 511 ? 511 : iy);
    int ix = (int)(px * 511.0f); ix = ix < 0 ? 0 : (ix > 511 ? 511 : ix);
    return ((unsigned)g << BIN_GBIT) | ((unsigned)iy << 3) | ((unsigned)ix >> 6);
}

__global__ __launch_bounds__(256)
void k_zero(unsigned* __restrict__ p, int n) {
    int i = blockIdx.x * blockDim.x + threadIdx.x;
    if (i < n) p[i] = 0u;
}

// One-pass bucket placement. cur[NBINS] is the overflow cursor.
__global__ __launch_bounds__(256)
void k_place(const float2* __restrict__ x, const int* __restrict__ hidx,
             unsigned* __restrict__ cur, unsigned* __restrict__ smeta, int N)
{
    int n = blockIdx.x * blockDim.x + threadIdx.x;
    if (n >= N) return;
    float2 p = x[n];
    int g = hidx[n];
    unsigned b = bin_of(p.x, p.y, g);
    unsigned pos = atomicAdd(&cur[b], 1u);
    unsigned slot;
    if (pos < CAP) {
        slot = b * CAP + pos;
    } else {
        unsigned o = atomicAdd(&cur[NBINS], 1u);   // o < N always
        slot = (unsigned)SLOTS + o;
    }
    smeta[slot] = (unsigned)n | ((unsigned)g << 24);   // N < 16.7M fits 24 bits
}

// Main gather kernel over bucket slots (bin-major order == sorted order).
__global__ __launch_bounds__(256)
void hashgrid2d_slots(const unsigned* __restrict__ smeta,
                      const unsigned* __restrict__ cnt,   // cursor array (counts)
                      const float2* __restrict__ x,
                      const float2* __restrict__ feat,
                      float4* __restrict__ out,
                      ScalePack sp, int N)
{
    // Bijective XCD-chunked swizzle: each XCD's L2 owns a contiguous y-band.
    int nwg = gridDim.x;
    int orig = blockIdx.x;
    int q = nwg >> 3, r = nwg & 7;
    int xcd = orig & 7, loc = orig >> 3;
    int bid = (xcd < r ? xcd * (q + 1) : r * (q + 1) + (xcd - r) * q) + loc;

    int idx = bid * 256 + (int)threadIdx.x;

    unsigned meta;
    if (idx < SLOTS) {
        unsigned bin  = (unsigned)idx / CAP;
        unsigned slot = (unsigned)idx - bin * CAP;
        unsigned c = cnt[bin];
        if (c > CAP) c = CAP;
        if (slot >= c) return;                 // ~1/3 of waves exit whole
        meta = smeta[idx];
    } else {
        unsigned ov = (unsigned)(idx - SLOTS);
        if (ov >= cnt[NBINS]) return;          // overflow ~always 0
        meta = smeta[idx];
    }

    int g  = (int)(meta >> 24);
    int no = (int)(meta & 0xFFFFFFu);
    float2 p = x[no];
    float px = p.x, py = p.y;
    const float2* fb = feat + (size_t)g * ((size_t)NL * TS);

    float of[2 * NL];

    #pragma unroll 4
    for (int l = 0; l < NL; ++l) {
        float s  = sp.s[l];
        float fx = px * s;
        float fy = py * s;
        float fx0 = floorf(fx), fy0 = floorf(fy);
        float wx = fx - fx0, wy = fy - fy0;
        unsigned ix = (unsigned)(int)fx0;
        unsigned iy = (unsigned)(int)fy0;
        unsigned hy0 = iy * PRIME;
        unsigned hy1 = (iy + 1u) * PRIME;

        const float2* tab = fb + (size_t)l * TS;
        float2 c00 = tab[( ix       ^ hy0) & TMASK];
        float2 c10 = tab[((ix + 1u) ^ hy0) & TMASK];
        float2 c01 = tab[( ix       ^ hy1) & TMASK];
        float2 c11 = tab[((ix + 1u) ^ hy1) & TMASK];

        float w00 = (1.f - wx) * (1.f - wy);
        float w10 = wx * (1.f - wy);
        float w01 = (1.f - wx) * wy;
        float w11 = wx * wy;

        of[2 * l]     = w00 * c00.x + w10 * c10.x + w01 * c01.x + w11 * c11.x;
        of[2 * l + 1] = w00 * c00.y + w10 * c10.y + w01 * c01.y + w11 * c11.y;
    }

    // Nontemporal: 125 MB output stream must not evict table lines from L2.
    f4* op = reinterpret_cast<f4*>(out + (size_t)no * 8);
    #pragma unroll
    for (int qq = 0; qq < 8; ++qq) {
        f4 v = { of[4 * qq], of[4 * qq + 1], of[4 * qq + 2], of[4 * qq + 3] };
        __builtin_nontemporal_store(v, op + qq);
    }
}

// ---------------- direct fallback (no workspace) ----------------------------
__global__ __launch_bounds__(256)
void hashgrid2d_fwd(const float2* __restrict__ x,
                    const float2* __restrict__ feat,
                    const int* __restrict__ hidx,
                    float4* __restrict__ out,
                    ScalePack sp, int N)
{
    int n = blockIdx.x * blockDim.x + threadIdx.x;
    if (n >= N) return;

    float2 p = x[n];
    float px = p.x, py = p.y;
    int g = hidx[n];
    const float2* fb = feat + (size_t)g * ((size_t)NL * TS);

    float of[2 * NL];

    #pragma unroll 4
    for (int l = 0; l < NL; ++l) {
        float s  = sp.s[l];
        float fx = px * s;
        float fy = py * s;
        float fx0 = floorf(fx), fy0 = floorf(fy);
        float wx = fx - fx0, wy = fy - fy0;
        unsigned ix = (unsigned)(int)fx0;
        unsigned iy = (unsigned)(int)fy0;
        unsigned hy0 = iy * PRIME;
        unsigned hy1 = (iy + 1u) * PRIME;

        const float2* tab = fb + (size_t)l * TS;
        float2 c00 = tab[( ix       ^ hy0) & TMASK];
        float2 c10 = tab[((ix + 1u) ^ hy0) & TMASK];
        float2 c01 = tab[( ix       ^ hy1) & TMASK];
        float2 c11 = tab[((ix + 1u) ^ hy1) & TMASK];

        float w00 = (1.f - wx) * (1.f - wy);
        float w10 = wx * (1.f - wy);
        float w01 = (1.f - wx) * wy;
        float w11 = wx * wy;

        of[2 * l]     = w00 * c00.x + w10 * c10.x + w01 * c01.x + w11 * c11.x;
        of[2 * l + 1] = w00 * c00.y + w10 * c10.y + w01 * c01.y + w11 * c11.y;
    }

    float4* op = out + (size_t)n * 8;
    #pragma unroll
    for (int qq = 0; qq < 8; ++qq)
        op[qq] = make_float4(of[4 * qq], of[4 * qq + 1], of[4 * qq + 2], of[4 * qq + 3]);
}

extern "C" void kernel_launch(void* const* d_in, const int* in_sizes, int n_in,
                              void* d_out, int out_size, void* d_ws, size_t ws_size,
                              hipStream_t stream) {
    const float2* x    = (const float2*)d_in[0];   // fp32, (N,2)
    const float2* feat = (const float2*)d_in[1];   // fp32, (2,16,T,2)
    const int*    hidx = (const int*)d_in[2];      // int32, (N,1)
    int N = in_sizes[0] / 2;

    // Replicate reference _resolutions() exactly (double log/exp/pow, same
    // libm as CPython, truncating int()). Levels 3,6,9,12,15 are 1 ulp off
    // exact powers of two — do not hardcode.
    ScalePack sp;
    double b = exp((log(512.0) - log(16.0)) / 15.0);
    for (int i = 0; i < NL; ++i) {
        int r = (int)(16.0 * pow(b, (double)i));
        sp.s[i] = (float)(r - 1);
    }

    int threads = 256;
    int blocks = (N + threads - 1) / threads;

    // Workspace layout: cursors (NBINS+1, padded to 64KB) | smeta slots+overflow
    size_t curB  = 65536;
    size_t metaB = ((size_t)SLOTS + (size_t)N) * 4;
    size_t need  = curB + metaB;                 // ~10.4 MB at N=1e6

    if (d_ws != nullptr && ws_size >= need && N < (1 << 24)) {
        unsigned* cur   = (unsigned*)d_ws;
        unsigned* smeta = (unsigned*)((char*)d_ws + curB);

        hipLaunchKernelGGL(k_zero, dim3((NBINS + 1 + 255) / 256), dim3(256), 0, stream,
                           cur, NBINS + 1);
        hipLaunchKernelGGL(k_place, dim3(blocks), dim3(threads), 0, stream,
                           x, hidx, cur, smeta, N);
        int total = SLOTS + N;
        int mblocks = (total + threads - 1) / threads;
        hipLaunchKernelGGL(hashgrid2d_slots, dim3(mblocks), dim3(threads), 0, stream,
                           smeta, cur, x, feat, (float4*)d_out, sp, N);
    } else {
        hipLaunchKernelGGL(hashgrid2d_fwd, dim3(blocks), dim3(threads), 0, stream,
                           x, feat, hidx, (float4*)d_out, sp, N);
    }
}

// Round 5
// 358.028 us; speedup vs baseline: 1.4813x; 1.2505x over previous
//
#include <hip/hip_runtime.h>
#include <math.h>

#define NL 16
#define TS (1u << 19)
#define TMASK (TS - 1u)
#define PRIME 2654435761u

// Spatial bins: g (1 bit) | iy_finest (9 bits) | ix_chunk (3 bits) = 8192 bins.
// hash = ix ^ (iy*PRIME): x-adjacent corners share cache lines, y-adjacent
// corners jump randomly -> cluster by (g, row, x-chunk).
//
// Counting sort with XCD-LOCAL atomics: 8 cursor copies (copy-major, 32 KB
// each, line-disjoint). Blocks use copy (blockIdx&7); dispatch round-robins
// blocks across the 8 XCDs, so each copy's cache lines stay in one XCD's L2
// -> no cross-XCD line ping-pong (round-4 post-mortem: 1M shared-counter
// atomics cost ~200 us from exactly that). Hist and scatter use the SAME
// grid shape and point->copy mapping, so per-(copy,bin) counts are exact.
#define NBINS 8192
#define BIN_GBIT 12
#define NCOPY 8

struct ScalePack { float s[NL]; };

__device__ __forceinline__ unsigned bin_of(float px, float py, int g) {
    int iy = (int)(py * 511.0f); iy = iy < 0 ? 0 : (iy > 511 ? 511 : iy);
    int ix = (int)(px * 511.0f); ix = ix < 0 ? 0 : (ix > 511 ? 511 : ix);
    return ((unsigned)g << BIN_GBIT) | ((unsigned)iy << 3) | ((unsigned)ix >> 6);
}

__global__ __launch_bounds__(256)
void k_zero(unsigned* __restrict__ p, int n) {
    int i = blockIdx.x * blockDim.x + threadIdx.x;
    if (i < n) p[i] = 0u;
}

// Pass 1: per-(copy,bin) histogram. 1 point/thread; copy = blockIdx&7.
__global__ __launch_bounds__(256)
void k_hist8(const float2* __restrict__ x, const int* __restrict__ hidx,
             unsigned* __restrict__ hist, int N)
{
    int n = blockIdx.x * 256 + threadIdx.x;
    if (n >= N) return;
    float2 p = x[n];
    unsigned b = bin_of(p.x, p.y, hidx[n]);
    unsigned c = (unsigned)blockIdx.x & (NCOPY - 1);
    atomicAdd(&hist[c * NBINS + b], 1u);
}

// Pass 2: in-place exclusive scan over (bin-major, copy-minor) order.
// Single block, 1024 threads x 8 bins each; converts counts -> start cursors.
__global__ __launch_bounds__(1024)
void k_scan8(unsigned* __restrict__ hist)
{
    __shared__ unsigned part[1024];
    int t = threadIdx.x;
    int b0 = t * 8;

    unsigned s = 0;
    #pragma unroll
    for (int i = 0; i < 8; ++i) {
        int b = b0 + i;
        #pragma unroll
        for (int c = 0; c < NCOPY; ++c) s += hist[c * NBINS + b];
    }
    part[t] = s;
    __syncthreads();
    for (int d = 1; d < 1024; d <<= 1) {
        unsigned add = (t >= d) ? part[t - d] : 0u;
        __syncthreads();
        part[t] += add;
        __syncthreads();
    }
    unsigned running = t ? part[t - 1] : 0u;

    #pragma unroll
    for (int i = 0; i < 8; ++i) {
        int b = b0 + i;
        unsigned h[NCOPY];
        #pragma unroll
        for (int c = 0; c < NCOPY; ++c) h[c] = hist[c * NBINS + b];
        #pragma unroll
        for (int c = 0; c < NCOPY; ++c) {
            hist[c * NBINS + b] = running;
            running += h[c];
        }
    }
}

// Pass 3: scatter to packed sorted arrays. Same mapping as k_hist8.
__global__ __launch_bounds__(256)
void k_scatter8(const float2* __restrict__ x, const int* __restrict__ hidx,
                unsigned* __restrict__ cur,
                float2* __restrict__ sxy, unsigned* __restrict__ smeta, int N)
{
    int n = blockIdx.x * 256 + threadIdx.x;
    if (n >= N) return;
    float2 p = x[n];
    int g = hidx[n];
    unsigned b = bin_of(p.x, p.y, g);
    unsigned c = (unsigned)blockIdx.x & (NCOPY - 1);
    unsigned pos = atomicAdd(&cur[c * NBINS + b], 1u);
    sxy[pos] = p;
    smeta[pos] = (unsigned)n | ((unsigned)g << 24);   // N < 16.7M fits 24 bits
}

// Main gather kernel over sorted points — EXACT round-1 structure (measured
// 83 us): packed sxy read, plain float4 stores (nontemporal stores tripled
// WRITE_SIZE in round 4 — do not reintroduce).
__global__ __launch_bounds__(256)
void hashgrid2d_sorted(const float2* __restrict__ sxy,
                       const unsigned* __restrict__ smeta,
                       const float2* __restrict__ feat,
                       float4* __restrict__ out,
                       ScalePack sp, int N)
{
    // Bijective XCD-chunked swizzle: each XCD's L2 owns a contiguous y-band.
    int nwg = gridDim.x;
    int orig = blockIdx.x;
    int q = nwg >> 3, r = nwg & 7;
    int xcd = orig & 7, loc = orig >> 3;
    int bid = (xcd < r ? xcd * (q + 1) : r * (q + 1) + (xcd - r) * q) + loc;

    int n = bid * 256 + (int)threadIdx.x;
    if (n >= N) return;

    float2 p = sxy[n];
    unsigned meta = smeta[n];
    int g  = (int)(meta >> 24);
    int no = (int)(meta & 0xFFFFFFu);
    float px = p.x, py = p.y;
    const float2* fb = feat + (size_t)g * ((size_t)NL * TS);

    float of[2 * NL];

    #pragma unroll 4
    for (int l = 0; l < NL; ++l) {
        float s  = sp.s[l];
        float fx = px * s;
        float fy = py * s;
        float fx0 = floorf(fx), fy0 = floorf(fy);
        float wx = fx - fx0, wy = fy - fy0;
        unsigned ix = (unsigned)(int)fx0;
        unsigned iy = (unsigned)(int)fy0;
        unsigned hy0 = iy * PRIME;
        unsigned hy1 = (iy + 1u) * PRIME;

        const float2* tab = fb + (size_t)l * TS;
        float2 c00 = tab[( ix       ^ hy0) & TMASK];
        float2 c10 = tab[((ix + 1u) ^ hy0) & TMASK];
        float2 c01 = tab[( ix       ^ hy1) & TMASK];
        float2 c11 = tab[((ix + 1u) ^ hy1) & TMASK];

        float w00 = (1.f - wx) * (1.f - wy);
        float w10 = wx * (1.f - wy);
        float w01 = (1.f - wx) * wy;
        float w11 = wx * wy;

        of[2 * l]     = w00 * c00.x + w10 * c10.x + w01 * c01.x + w11 * c11.x;
        of[2 * l + 1] = w00 * c00.y + w10 * c10.y + w01 * c01.y + w11 * c11.y;
    }

    float4* op = out + (size_t)no * 8;
    #pragma unroll
    for (int qq = 0; qq < 8; ++qq)
        op[qq] = make_float4(of[4 * qq], of[4 * qq + 1], of[4 * qq + 2], of[4 * qq + 3]);
}

// ---------------- direct fallback (no workspace) ----------------------------
__global__ __launch_bounds__(256)
void hashgrid2d_fwd(const float2* __restrict__ x,
                    const float2* __restrict__ feat,
                    const int* __restrict__ hidx,
                    float4* __restrict__ out,
                    ScalePack sp, int N)
{
    int n = blockIdx.x * blockDim.x + threadIdx.x;
    if (n >= N) return;

    float2 p = x[n];
    float px = p.x, py = p.y;
    int g = hidx[n];
    const float2* fb = feat + (size_t)g * ((size_t)NL * TS);

    float of[2 * NL];

    #pragma unroll 4
    for (int l = 0; l < NL; ++l) {
        float s  = sp.s[l];
        float fx = px * s;
        float fy = py * s;
        float fx0 = floorf(fx), fy0 = floorf(fy);
        float wx = fx - fx0, wy = fy - fy0;
        unsigned ix = (unsigned)(int)fx0;
        unsigned iy = (unsigned)(int)fy0;
        unsigned hy0 = iy * PRIME;
        unsigned hy1 = (iy + 1u) * PRIME;

        const float2* tab = fb + (size_t)l * TS;
        float2 c00 = tab[( ix       ^ hy0) & TMASK];
        float2 c10 = tab[((ix + 1u) ^ hy0) & TMASK];
        float2 c01 = tab[( ix       ^ hy1) & TMASK];
        float2 c11 = tab[((ix + 1u) ^ hy1) & TMASK];

        float w00 = (1.f - wx) * (1.f - wy);
        float w10 = wx * (1.f - wy);
        float w01 = (1.f - wx) * wy;
        float w11 = wx * wy;

        of[2 * l]     = w00 * c00.x + w10 * c10.x + w01 * c01.x + w11 * c11.x;
        of[2 * l + 1] = w00 * c00.y + w10 * c10.y + w01 * c01.y + w11 * c11.y;
    }

    float4* op = out + (size_t)n * 8;
    #pragma unroll
    for (int qq = 0; qq < 8; ++qq)
        op[qq] = make_float4(of[4 * qq], of[4 * qq + 1], of[4 * qq + 2], of[4 * qq + 3]);
}

extern "C" void kernel_launch(void* const* d_in, const int* in_sizes, int n_in,
                              void* d_out, int out_size, void* d_ws, size_t ws_size,
                              hipStream_t stream) {
    const float2* x    = (const float2*)d_in[0];   // fp32, (N,2)
    const float2* feat = (const float2*)d_in[1];   // fp32, (2,16,T,2)
    const int*    hidx = (const int*)d_in[2];      // int32, (N,1)
    int N = in_sizes[0] / 2;

    // Replicate reference _resolutions() exactly (double log/exp/pow, same
    // libm as CPython, truncating int()). Levels 3,6,9,12,15 are 1 ulp off
    // exact powers of two — do not hardcode.
    ScalePack sp;
    double b = exp((log(512.0) - log(16.0)) / 15.0);
    for (int i = 0; i < NL; ++i) {
        int r = (int)(16.0 * pow(b, (double)i));
        sp.s[i] = (float)(r - 1);
    }

    int threads = 256;
    int blocks = (N + threads - 1) / threads;

    // Workspace: cur[8][NBINS] (256 KB) | sxy (8N B) | smeta (4N B)
    size_t curB  = (size_t)NCOPY * NBINS * 4;
    size_t xyB   = (size_t)N * 8;
    size_t metaB = (size_t)N * 4;
    size_t need  = curB + xyB + metaB;           // ~12.26 MB at N=1e6

    if (d_ws != nullptr && ws_size >= need && N < (1 << 24)) {
        unsigned* cur   = (unsigned*)d_ws;
        float2*   sxy   = (float2*)((char*)d_ws + curB);
        unsigned* smeta = (unsigned*)((char*)d_ws + curB + xyB);

        hipLaunchKernelGGL(k_zero, dim3((NCOPY * NBINS + 255) / 256), dim3(256), 0,
                           stream, cur, NCOPY * NBINS);
        hipLaunchKernelGGL(k_hist8, dim3(blocks), dim3(threads), 0, stream,
                           x, hidx, cur, N);
        hipLaunchKernelGGL(k_scan8, dim3(1), dim3(1024), 0, stream, cur);
        hipLaunchKernelGGL(k_scatter8, dim3(blocks), dim3(threads), 0, stream,
                           x, hidx, cur, sxy, smeta, N);
        hipLaunchKernelGGL(hashgrid2d_sorted, dim3(blocks), dim3(threads), 0, stream,
                           sxy, smeta, feat, (float4*)d_out, sp, N);
    } else {
        hipLaunchKernelGGL(hashgrid2d_fwd, dim3(blocks), dim3(threads), 0, stream,
                           x, feat, hidx, (float4*)d_out, sp, N);
    }
}

// Round 6
// 327.961 us; speedup vs baseline: 1.6171x; 1.0917x over previous
//
#include <hip/hip_runtime.h>
#include <math.h>

#define NL 16
#define TS (1u << 19)
#define TMASK (TS - 1u)
#define PRIME 2654435761u

// ---- new atomic-free sort params ----
// bins: g (1 bit) | iy_finest (9 bits) | ix_chunk (2 bits) = 4096 bins.
// hash = ix ^ (iy*PRIME): x-adjacent corners share cache lines, y-adjacent
// corners jump randomly -> cluster by (g, row, x-chunk).
#define SBINS 4096
#define SBLK  256           // stat blocks for hist/scatter (grid-stride)

// ---- old (round-5 proven) path params ----
#define OBINS 8192
#define NCOPY 8

struct ScalePack { float s[NL]; };

__device__ __forceinline__ unsigned bin4k_of(float px, float py, int g) {
    int iy = (int)(py * 511.0f); iy = iy < 0 ? 0 : (iy > 511 ? 511 : iy);
    int ix = (int)(px * 511.0f); ix = ix < 0 ? 0 : (ix > 511 ? 511 : ix);
    return ((unsigned)g << 11) | ((unsigned)iy << 2) | ((unsigned)ix >> 7);
}

__device__ __forceinline__ unsigned bin8k_of(float px, float py, int g) {
    int iy = (int)(py * 511.0f); iy = iy < 0 ? 0 : (iy > 511 ? 511 : iy);
    int ix = (int)(px * 511.0f); ix = ix < 0 ? 0 : (ix > 511 ? 511 : ix);
    return ((unsigned)g << 12) | ((unsigned)iy << 3) | ((unsigned)ix >> 6);
}

// ================= NEW PATH: exact counting sort, zero device atomics =======
// (Round-4/5 post-mortem: ~1M device-scope atomics cost ~60-80 us/pass flat,
//  independent of address spread -> they execute at the memory-side coherence
//  point. All atomics below are LDS-scope.)

// Pass 1: per-block LDS histogram -> coalesced H[blk][SBINS] row.
__global__ __launch_bounds__(256)
void k_hist_b(const float2* __restrict__ x, const int* __restrict__ hidx,
              unsigned* __restrict__ H, int N)
{
    __shared__ unsigned lh[SBINS];
    int t = threadIdx.x;
    #pragma unroll
    for (int i = t; i < SBINS; i += 256) lh[i] = 0u;
    __syncthreads();

    for (int n = blockIdx.x * 256 + t; n < N; n += SBLK * 256) {
        float2 p = x[n];
        atomicAdd(&lh[bin4k_of(p.x, p.y, hidx[n])], 1u);   // LDS atomic
    }
    __syncthreads();

    unsigned* row = H + (size_t)blockIdx.x * SBINS;
    #pragma unroll
    for (int i = t; i < SBINS; i += 256) row[i] = lh[i];
}

// Pass 2a: per-bin exclusive scan over the 256 blocks (one block per bin).
// H[blk][bin] <- sum of H[b<blk][bin]; binTotal[bin] <- full sum.
__global__ __launch_bounds__(256)
void k_s1(unsigned* __restrict__ H, unsigned* __restrict__ binTotal)
{
    __shared__ unsigned part[256];
    int bin = blockIdx.x;
    int t = threadIdx.x;
    unsigned v = H[(size_t)t * SBINS + bin];
    part[t] = v;
    __syncthreads();
    for (int d = 1; d < 256; d <<= 1) {
        unsigned add = (t >= d) ? part[t - d] : 0u;
        __syncthreads();
        part[t] += add;
        __syncthreads();
    }
    unsigned incl = part[t];
    H[(size_t)t * SBINS + bin] = incl - v;      // exclusive
    if (t == 255) binTotal[bin] = incl;
}

// Pass 2b: exclusive scan of binTotal[SBINS] -> binBase. One block, 1024 thr.
__global__ __launch_bounds__(1024)
void k_s2(const unsigned* __restrict__ binTotal, unsigned* __restrict__ binBase)
{
    __shared__ unsigned part[1024];
    int t = threadIdx.x;
    unsigned v[4];
    unsigned s = 0;
    #pragma unroll
    for (int i = 0; i < 4; ++i) { v[i] = binTotal[t * 4 + i]; s += v[i]; }
    part[t] = s;
    __syncthreads();
    for (int d = 1; d < 1024; d <<= 1) {
        unsigned add = (t >= d) ? part[t - d] : 0u;
        __syncthreads();
        part[t] += add;
        __syncthreads();
    }
    unsigned base = t ? part[t - 1] : 0u;
    #pragma unroll
    for (int i = 0; i < 4; ++i) { binBase[t * 4 + i] = base; base += v[i]; }
}

// Pass 3: scatter with LDS cursors (deterministic segment per (blk,bin)).
// MUST traverse points with the identical grid-stride mapping as k_hist_b.
__global__ __launch_bounds__(256)
void k_scatter_b(const float2* __restrict__ x, const int* __restrict__ hidx,
                 const unsigned* __restrict__ H, const unsigned* __restrict__ binBase,
                 float2* __restrict__ sxy, unsigned* __restrict__ smeta, int N)
{
    __shared__ unsigned cur[SBINS];
    int t = threadIdx.x;
    const unsigned* row = H + (size_t)blockIdx.x * SBINS;
    #pragma unroll
    for (int i = t; i < SBINS; i += 256) cur[i] = binBase[i] + row[i];
    __syncthreads();

    for (int n = blockIdx.x * 256 + t; n < N; n += SBLK * 256) {
        float2 p = x[n];
        int g = hidx[n];
        unsigned b = bin4k_of(p.x, p.y, g);
        unsigned pos = atomicAdd(&cur[b], 1u);             // LDS atomic
        sxy[pos] = p;
        smeta[pos] = (unsigned)n | ((unsigned)g << 24);    // N < 16.7M
    }
}

// ================= OLD PATH (round-5 proven, 8-copy global atomics) =========
__global__ __launch_bounds__(256)
void k_zero(unsigned* __restrict__ p, int n) {
    int i = blockIdx.x * blockDim.x + threadIdx.x;
    if (i < n) p[i] = 0u;
}

__global__ __launch_bounds__(256)
void k_hist8(const float2* __restrict__ x, const int* __restrict__ hidx,
             unsigned* __restrict__ hist, int N)
{
    int n = blockIdx.x * 256 + threadIdx.x;
    if (n >= N) return;
    float2 p = x[n];
    unsigned b = bin8k_of(p.x, p.y, hidx[n]);
    unsigned c = (unsigned)blockIdx.x & (NCOPY - 1);
    atomicAdd(&hist[c * OBINS + b], 1u);
}

__global__ __launch_bounds__(1024)
void k_scan8(unsigned* __restrict__ hist)
{
    __shared__ unsigned part[1024];
    int t = threadIdx.x;
    int b0 = t * 8;
    unsigned s = 0;
    #pragma unroll
    for (int i = 0; i < 8; ++i) {
        int b = b0 + i;
        #pragma unroll
        for (int c = 0; c < NCOPY; ++c) s += hist[c * OBINS + b];
    }
    part[t] = s;
    __syncthreads();
    for (int d = 1; d < 1024; d <<= 1) {
        unsigned add = (t >= d) ? part[t - d] : 0u;
        __syncthreads();
        part[t] += add;
        __syncthreads();
    }
    unsigned running = t ? part[t - 1] : 0u;
    #pragma unroll
    for (int i = 0; i < 8; ++i) {
        int b = b0 + i;
        unsigned h[NCOPY];
        #pragma unroll
        for (int c = 0; c < NCOPY; ++c) h[c] = hist[c * OBINS + b];
        #pragma unroll
        for (int c = 0; c < NCOPY; ++c) {
            hist[c * OBINS + b] = running;
            running += h[c];
        }
    }
}

__global__ __launch_bounds__(256)
void k_scatter8(const float2* __restrict__ x, const int* __restrict__ hidx,
                unsigned* __restrict__ cur,
                float2* __restrict__ sxy, unsigned* __restrict__ smeta, int N)
{
    int n = blockIdx.x * 256 + threadIdx.x;
    if (n >= N) return;
    float2 p = x[n];
    int g = hidx[n];
    unsigned b = bin8k_of(p.x, p.y, g);
    unsigned c = (unsigned)blockIdx.x & (NCOPY - 1);
    unsigned pos = atomicAdd(&cur[c * OBINS + b], 1u);
    sxy[pos] = p;
    smeta[pos] = (unsigned)n | ((unsigned)g << 24);
}

// ================= main gather kernel (verified 83-85 us) ===================
__global__ __launch_bounds__(256)
void hashgrid2d_sorted(const float2* __restrict__ sxy,
                       const unsigned* __restrict__ smeta,
                       const float2* __restrict__ feat,
                       float4* __restrict__ out,
                       ScalePack sp, int N)
{
    // Bijective XCD-chunked swizzle: each XCD's L2 owns a contiguous y-band.
    int nwg = gridDim.x;
    int orig = blockIdx.x;
    int q = nwg >> 3, r = nwg & 7;
    int xcd = orig & 7, loc = orig >> 3;
    int bid = (xcd < r ? xcd * (q + 1) : r * (q + 1) + (xcd - r) * q) + loc;

    int n = bid * 256 + (int)threadIdx.x;
    if (n >= N) return;

    float2 p = sxy[n];
    unsigned meta = smeta[n];
    int g  = (int)(meta >> 24);
    int no = (int)(meta & 0xFFFFFFu);
    float px = p.x, py = p.y;
    const float2* fb = feat + (size_t)g * ((size_t)NL * TS);

    float of[2 * NL];

    #pragma unroll 4
    for (int l = 0; l < NL; ++l) {
        float s  = sp.s[l];
        float fx = px * s;
        float fy = py * s;
        float fx0 = floorf(fx), fy0 = floorf(fy);
        float wx = fx - fx0, wy = fy - fy0;
        unsigned ix = (unsigned)(int)fx0;
        unsigned iy = (unsigned)(int)fy0;
        unsigned hy0 = iy * PRIME;
        unsigned hy1 = (iy + 1u) * PRIME;

        const float2* tab = fb + (size_t)l * TS;
        float2 c00 = tab[( ix       ^ hy0) & TMASK];
        float2 c10 = tab[((ix + 1u) ^ hy0) & TMASK];
        float2 c01 = tab[( ix       ^ hy1) & TMASK];
        float2 c11 = tab[((ix + 1u) ^ hy1) & TMASK];

        float w00 = (1.f - wx) * (1.f - wy);
        float w10 = wx * (1.f - wy);
        float w01 = (1.f - wx) * wy;
        float w11 = wx * wy;

        of[2 * l]     = w00 * c00.x + w10 * c10.x + w01 * c01.x + w11 * c11.x;
        of[2 * l + 1] = w00 * c00.y + w10 * c10.y + w01 * c01.y + w11 * c11.y;
    }

    float4* op = out + (size_t)no * 8;
    #pragma unroll
    for (int qq = 0; qq < 8; ++qq)
        op[qq] = make_float4(of[4 * qq], of[4 * qq + 1], of[4 * qq + 2], of[4 * qq + 3]);
}

// ---------------- direct fallback (no workspace) ----------------------------
__global__ __launch_bounds__(256)
void hashgrid2d_fwd(const float2* __restrict__ x,
                    const float2* __restrict__ feat,
                    const int* __restrict__ hidx,
                    float4* __restrict__ out,
                    ScalePack sp, int N)
{
    int n = blockIdx.x * blockDim.x + threadIdx.x;
    if (n >= N) return;

    float2 p = x[n];
    float px = p.x, py = p.y;
    int g = hidx[n];
    const float2* fb = feat + (size_t)g * ((size_t)NL * TS);

    float of[2 * NL];

    #pragma unroll 4
    for (int l = 0; l < NL; ++l) {
        float s  = sp.s[l];
        float fx = px * s;
        float fy = py * s;
        float fx0 = floorf(fx), fy0 = floorf(fy);
        float wx = fx - fx0, wy = fy - fy0;
        unsigned ix = (unsigned)(int)fx0;
        unsigned iy = (unsigned)(int)fy0;
        unsigned hy0 = iy * PRIME;
        unsigned hy1 = (iy + 1u) * PRIME;

        const float2* tab = fb + (size_t)l * TS;
        float2 c00 = tab[( ix       ^ hy0) & TMASK];
        float2 c10 = tab[((ix + 1u) ^ hy0) & TMASK];
        float2 c01 = tab[( ix       ^ hy1) & TMASK];
        float2 c11 = tab[((ix + 1u) ^ hy1) & TMASK];

        float w00 = (1.f - wx) * (1.f - wy);
        float w10 = wx * (1.f - wy);
        float w01 = (1.f - wx) * wy;
        float w11 = wx * wy;

        of[2 * l]     = w00 * c00.x + w10 * c10.x + w01 * c01.x + w11 * c11.x;
        of[2 * l + 1] = w00 * c00.y + w10 * c10.y + w01 * c01.y + w11 * c11.y;
    }

    float4* op = out + (size_t)n * 8;
    #pragma unroll
    for (int qq = 0; qq < 8; ++qq)
        op[qq] = make_float4(of[4 * qq], of[4 * qq + 1], of[4 * qq + 2], of[4 * qq + 3]);
}

extern "C" void kernel_launch(void* const* d_in, const int* in_sizes, int n_in,
                              void* d_out, int out_size, void* d_ws, size_t ws_size,
                              hipStream_t stream) {
    const float2* x    = (const float2*)d_in[0];   // fp32, (N,2)
    const float2* feat = (const float2*)d_in[1];   // fp32, (2,16,T,2)
    const int*    hidx = (const int*)d_in[2];      // int32, (N,1)
    int N = in_sizes[0] / 2;

    // Replicate reference _resolutions() exactly (double log/exp/pow, same
    // libm as CPython, truncating int()). Levels 3,6,9,12,15 are 1 ulp off
    // exact powers of two — do not hardcode.
    ScalePack sp;
    double b = exp((log(512.0) - log(16.0)) / 15.0);
    for (int i = 0; i < NL; ++i) {
        int r = (int)(16.0 * pow(b, (double)i));
        sp.s[i] = (float)(r - 1);
    }

    int threads = 256;
    int blocks = (N + threads - 1) / threads;

    size_t xyB   = (size_t)N * 8;
    size_t metaB = (size_t)N * 4;

    // New path: H[SBLK][SBINS] | binTotal | binBase | sxy | smeta  (~16.3 MB)
    size_t HB       = (size_t)SBLK * SBINS * 4;
    size_t need_new = HB + (size_t)SBINS * 4 * 2 + xyB + metaB;
    // Old path: cur[8][OBINS] | sxy | smeta  (~12.3 MB, proven to fit)
    size_t curB     = (size_t)NCOPY * OBINS * 4;
    size_t need_old = curB + xyB + metaB;

    if (d_ws != nullptr && ws_size >= need_new && N < (1 << 24)) {
        unsigned* H        = (unsigned*)d_ws;
        unsigned* binTotal = (unsigned*)((char*)d_ws + HB);
        unsigned* binBase  = binTotal + SBINS;
        float2*   sxy      = (float2*)((char*)d_ws + HB + (size_t)SBINS * 8);
        unsigned* smeta    = (unsigned*)((char*)d_ws + HB + (size_t)SBINS * 8 + xyB);

        hipLaunchKernelGGL(k_hist_b, dim3(SBLK), dim3(256), 0, stream,
                           x, hidx, H, N);
        hipLaunchKernelGGL(k_s1, dim3(SBINS), dim3(256), 0, stream, H, binTotal);
        hipLaunchKernelGGL(k_s2, dim3(1), dim3(1024), 0, stream, binTotal, binBase);
        hipLaunchKernelGGL(k_scatter_b, dim3(SBLK), dim3(256), 0, stream,
                           x, hidx, H, binBase, sxy, smeta, N);
        hipLaunchKernelGGL(hashgrid2d_sorted, dim3(blocks), dim3(threads), 0, stream,
                           sxy, smeta, feat, (float4*)d_out, sp, N);
    } else if (d_ws != nullptr && ws_size >= need_old && N < (1 << 24)) {
        unsigned* cur   = (unsigned*)d_ws;
        float2*   sxy   = (float2*)((char*)d_ws + curB);
        unsigned* smeta = (unsigned*)((char*)d_ws + curB + xyB);

        hipLaunchKernelGGL(k_zero, dim3((NCOPY * OBINS + 255) / 256), dim3(256), 0,
                           stream, cur, NCOPY * OBINS);
        hipLaunchKernelGGL(k_hist8, dim3(blocks), dim3(threads), 0, stream,
                           x, hidx, cur, N);
        hipLaunchKernelGGL(k_scan8, dim3(1), dim3(1024), 0, stream, cur);
        hipLaunchKernelGGL(k_scatter8, dim3(blocks), dim3(threads), 0, stream,
                           x, hidx, cur, sxy, smeta, N);
        hipLaunchKernelGGL(hashgrid2d_sorted, dim3(blocks), dim3(threads), 0, stream,
                           sxy, smeta, feat, (float4*)d_out, sp, N);
    } else {
        hipLaunchKernelGGL(hashgrid2d_fwd, dim3(blocks), dim3(threads), 0, stream,
                           x, feat, hidx, (float4*)d_out, sp, N);
    }
}